// Round 6
// baseline (521.822 us; speedup 1.0000x reference)
//
#include <hip/hip_runtime.h>
#include <hip/hip_cooperative_groups.h>

namespace cg = cooperative_groups;

#define E_CONST 3
#define T_CONST 100
#define C10 10.0f
#define ALPHA_C 0.05f

struct Ptrs {
    const float* event_out;   // (E,S,T)
    const int*   et;          // (S,E)
    const int*   labs;        // (S,E)
    float* cumT;              // (E,T,S)
    float* expF;              // (E,T,S)  exp(+10 v) in perm order
    float* expB;              // (E,T,S)  exp(-10 v) in permB order
    int*   perm;              // (E,S)
    int*   permB;             // (E,S)
    int*   tlP;               // (E,S) metadata in perm-slot order
    int*   fstart;            // (E,T)
    int*   b1end;             // (E,T)
    int*   histK;             // (E,2T) ; histB = histK + E*2T (contiguous)
    int*   histB;             // (E,T)
    int*   cursK;             // (E,2T)
    int*   cursB;             // (E,T)
    float* acc;               // 1
    float* out;               // 1
    int S;
};

__device__ inline int waveInclScan(int v, int lane) {
    #pragma unroll
    for (int off = 1; off < 64; off <<= 1) {
        int n = __shfl_up(v, off, 64);
        if (lane >= off) v += n;
    }
    return v;
}

// ---------------------------------------------------------------------------
// One cooperative kernel, 6 phases separated by grid.sync():
//  0: zero hists+acc   1: cumsum->cumT + hist atomics (meta kept in register)
//  2: hist scans       3: counting-sort scatter (perm/permB/tlP)
//  4: permute+exp      5: pair sums (one query per wave) -> atomicAdd(acc)
//  6: out = alpha*acc
// ---------------------------------------------------------------------------
__global__ __launch_bounds__(256, 2) void fused_kernel(Ptrs P) {
    cg::grid_group grid = cg::this_grid();
    const int S = P.S;
    const int tid = threadIdx.x, bid = blockIdx.x;
    const int nThreads = (int)gridDim.x * 256;
    const int gthread = bid * 256 + tid;
    const int lane = tid & 63;
    const int wid  = tid >> 6;

    __shared__ int wsumK[4], wsumB[4];

    // ---- phase 0: zero histograms + accumulator (histK,histB contiguous)
    if (bid == 0) {
        for (int idx = tid; idx < E_CONST * 3 * T_CONST; idx += 256) P.histK[idx] = 0;
        if (tid == 0) P.acc[0] = 0.f;
    }
    grid.sync();

    // ---- phase 1: prep (register cumsum, transposed stores, hist atomics)
    int tlreg = 0;
    if (gthread < E_CONST * S) {
        const int i = gthread / S, s = gthread - i * S;
        const float4* __restrict__ row =
            reinterpret_cast<const float4*>(P.event_out + (size_t)gthread * T_CONST);
        float* __restrict__ base = P.cumT + (size_t)i * T_CONST * S + s;
        float run = 0.f;
        #pragma unroll
        for (int c = 0; c < T_CONST / 4; ++c) {
            const float4 v = row[c];
            const float c0 = run + v.x;
            const float c1 = c0 + v.y;
            const float c2 = c1 + v.z;
            const float c3 = c2 + v.w;
            base[(size_t)(4 * c + 0) * S] = c0;
            base[(size_t)(4 * c + 1) * S] = c1;
            base[(size_t)(4 * c + 2) * S] = c2;
            base[(size_t)(4 * c + 3) * S] = c3;
            run = c3;
        }
        const int t   = P.et[s * E_CONST + i];
        const int lab = P.labs[s * E_CONST + i];
        tlreg = (t & 0xffff) | (lab << 16);
        atomicAdd(&P.histK[i * 2 * T_CONST + t * 2 + (1 - lab)], 1);
        if (lab) atomicAdd(&P.histB[i * T_CONST + t], 1);
    }
    grid.sync();

    // ---- phase 2: parallel hist scans (blocks 0..2, one event each)
    if (bid < E_CONST) {
        const int i = bid;
        const int vK = (tid < 2 * T_CONST) ? P.histK[i * 2 * T_CONST + tid] : 0;
        int inclK = waveInclScan(vK, lane);
        const int vB = (tid < T_CONST) ? P.histB[i * T_CONST + tid] : 0;
        int inclB = waveInclScan(vB, lane);
        if (lane == 63) { wsumK[wid] = inclK; wsumB[wid] = inclB; }
        __syncthreads();
        int offK = 0, offB = 0;
        for (int w = 0; w < wid; ++w) { offK += wsumK[w]; offB += wsumB[w]; }
        inclK += offK; inclB += offB;
        const int exclK = inclK - vK;
        const int exclB = inclB - vB;
        if (tid < 2 * T_CONST) {
            P.cursK[i * 2 * T_CONST + tid] = exclK;
            if (tid & 1) P.fstart[i * T_CONST + (tid >> 1)] = exclK;  // bin 2t+1
        }
        if (tid < T_CONST) {
            P.cursB[i * T_CONST + tid] = exclB;
            P.b1end[i * T_CONST + tid] = inclB;
        }
    }
    grid.sync();

    // ---- phase 3: scatter (metadata still in register from phase 1)
    if (gthread < E_CONST * S) {
        const int i = gthread / S, s = gthread - i * S;
        const int t = tlreg & 0xffff, lab = tlreg >> 16;
        const int slot = atomicAdd(&P.cursK[i * 2 * T_CONST + t * 2 + (1 - lab)], 1);
        P.perm[i * S + slot] = s;
        P.tlP[i * S + slot]  = tlreg;
        if (lab) {
            const int sb = atomicAdd(&P.cursB[i * T_CONST + t], 1);
            P.permB[i * S + sb] = s;
        }
    }
    grid.sync();

    // ---- phase 4: permute + exp (one column per block, round-robin)
    for (int colIdx = bid; colIdx < E_CONST * T_CONST; colIdx += (int)gridDim.x) {
        const int i = colIdx / T_CONST;
        const float* __restrict__ col = P.cumT + (size_t)colIdx * S;
        const int n1 = P.b1end[i * T_CONST + T_CONST - 1];
        for (int idx = tid; idx < S + n1; idx += 256) {
            if (idx < S) {
                P.expF[(size_t)colIdx * S + idx] = __expf(C10 * col[P.perm[i * S + idx]]);
            } else {
                const int jb = idx - S;
                P.expB[(size_t)colIdx * S + jb] = __expf(-C10 * col[P.permB[i * S + jb]]);
            }
        }
    }
    grid.sync();

    // ---- phase 5: pair sums — one query per wave, grid-stride
    {
        const int nWaves = nThreads >> 6;
        const int waveId = gthread >> 6;
        float lane_total = 0.f;
        for (int q = waveId; q < E_CONST * S; q += nWaves) {
            const int i = q / S, j = q - i * S;
            const int tl = P.tlP[i * S + j];
            const int tk = tl & 0xffff;
            const int lk = tl >> 16;

            if (lk) {  // forward: suffix [fstart(tk), S) of expF col tk, e > thr
                const float* __restrict__ cp = P.expF + ((size_t)i * T_CONST + tk) * S;
                const float thr = cp[j];
                const int lo  = P.fstart[i * T_CONST + tk];
                const int loa = (lo + 3) & ~3;
                float ssum = 0.f;
                if (lane < loa - lo) { const float e = cp[lo + lane]; ssum += (e > thr) ? e : 0.f; }
                for (int p = loa + lane * 4; p < S; p += 256) {
                    const float4 v = *reinterpret_cast<const float4*>(cp + p);
                    ssum += (v.x > thr) ? v.x : 0.f;
                    ssum += (v.y > thr) ? v.y : 0.f;
                    ssum += (v.z > thr) ? v.z : 0.f;
                    ssum += (v.w > thr) ? v.w : 0.f;
                }
                lane_total += ssum * (1.0f / thr);
            }

            if (tk > 0) {  // backward: prefix [0, b1end(cb)) of expB col cb, e > 1/efk
                const int cb = lk ? tk - 1 : tk;
                const size_t cbase = ((size_t)i * T_CONST + cb) * S;
                const float efk = P.expF[cbase + j];
                const float thr = 1.0f / efk;
                const float* __restrict__ cp = P.expB + cbase;
                const int hi  = P.b1end[i * T_CONST + cb];
                const int hia = hi & ~3;
                float ssum = 0.f;
                for (int p = lane * 4; p < hia; p += 256) {
                    const float4 v = *reinterpret_cast<const float4*>(cp + p);
                    ssum += (v.x > thr) ? v.x : 0.f;
                    ssum += (v.y > thr) ? v.y : 0.f;
                    ssum += (v.z > thr) ? v.z : 0.f;
                    ssum += (v.w > thr) ? v.w : 0.f;
                }
                if (lane < hi - hia) { const float e = cp[hia + lane]; ssum += (e > thr) ? e : 0.f; }
                lane_total += ssum * efk;
            }
        }
        #pragma unroll
        for (int off = 32; off > 0; off >>= 1)
            lane_total += __shfl_down(lane_total, off, 64);
        if (lane == 0 && lane_total != 0.f) atomicAdd(P.acc, lane_total);
    }
    grid.sync();

    // ---- phase 6: single writer
    if (gthread == 0) P.out[0] = ALPHA_C * P.acc[0];
}

// ===========================================================================
// Fallback multi-kernel path (R5, proven) — used only if cooperative launch
// is unavailable.
// ===========================================================================
__global__ __launch_bounds__(64) void prep_kernel(
    const float* __restrict__ event_out, const int* __restrict__ et,
    const int* __restrict__ labs, float* __restrict__ cumT,
    int* __restrict__ tlA, int S)
{
    const int gid = blockIdx.x * 64 + threadIdx.x;
    const int i = gid / S;
    const int s = gid - i * S;
    const float4* __restrict__ row =
        reinterpret_cast<const float4*>(event_out + (size_t)gid * T_CONST);
    float* __restrict__ base = cumT + (size_t)i * T_CONST * S + s;
    float run = 0.f;
    #pragma unroll
    for (int c = 0; c < T_CONST / 4; ++c) {
        const float4 v = row[c];
        const float c0 = run + v.x;
        const float c1 = c0 + v.y;
        const float c2 = c1 + v.z;
        const float c3 = c2 + v.w;
        base[(size_t)(4 * c + 0) * S] = c0;
        base[(size_t)(4 * c + 1) * S] = c1;
        base[(size_t)(4 * c + 2) * S] = c2;
        base[(size_t)(4 * c + 3) * S] = c3;
        run = c3;
    }
    const int t   = et[s * E_CONST + i];
    const int lab = labs[s * E_CONST + i];
    tlA[i * S + s] = (t & 0xffff) | (lab << 16);
}

__global__ __launch_bounds__(256) void pair_kernel(
    const float* __restrict__ cumT, const int* __restrict__ tlA,
    float* __restrict__ partials, int S)
{
    const int bx = blockIdx.x;
    const int i = bx / S;
    const int k = bx - i * S;
    const int base = i * S;
    const int tlk = tlA[base + k];
    const int t_k = tlk & 0xffff;
    const int lab_k = tlk >> 16;
    const bool doF = (lab_k == 1);
    const bool doB = (t_k > 0);
    float sum = 0.f;
    if (doF || doB) {
        const int cb = lab_k ? (t_k > 0 ? t_k - 1 : 0) : t_k;
        const float* __restrict__ colF = cumT + ((size_t)i * T_CONST + t_k) * S;
        const float* __restrict__ colB = cumT + ((size_t)i * T_CONST + cb)  * S;
        const float vf_k = colF[k];
        const float vb_k = colB[k];
        const int* __restrict__ tlp = tlA + base;
        for (int s = threadIdx.x; s < S; s += 256) {
            const int tls = tlp[s];
            const int t_s = tls & 0xffff;
            const int lab_s = tls >> 16;
            if (doF) {
                const float vs = colF[s];
                const bool c = (t_s > t_k) | ((t_s == t_k) & (lab_s == 0));
                if (c & (vs > vf_k)) sum += __expf((vs - vf_k) * C10);
            }
            if (doB) {
                const float vs = colB[s];
                const bool c = (t_s <= cb) & (lab_s == 1);
                if (c & (vb_k > vs)) sum += __expf((vb_k - vs) * C10);
            }
        }
    }
    for (int off = 32; off > 0; off >>= 1) sum += __shfl_down(sum, off, 64);
    __shared__ float wsum[4];
    const int lane = threadIdx.x & 63, wd = threadIdx.x >> 6;
    if (lane == 0) wsum[wd] = sum;
    __syncthreads();
    if (threadIdx.x == 0) partials[bx] = wsum[0] + wsum[1] + wsum[2] + wsum[3];
}

__global__ __launch_bounds__(1024) void reduce_kernel(
    const float* __restrict__ partials, int n, float* __restrict__ out)
{
    float sum = 0.f;
    for (int idx = threadIdx.x; idx < n; idx += 1024) sum += partials[idx];
    for (int off = 32; off > 0; off >>= 1) sum += __shfl_down(sum, off, 64);
    __shared__ float wsum[16];
    const int lane = threadIdx.x & 63, wd = threadIdx.x >> 6;
    if (lane == 0) wsum[wd] = sum;
    __syncthreads();
    if (threadIdx.x == 0) {
        float t = 0.f;
        for (int w = 0; w < 16; ++w) t += wsum[w];
        out[0] = ALPHA_C * t;
    }
}

extern "C" void kernel_launch(void* const* d_in, const int* in_sizes, int n_in,
                              void* d_out, int out_size, void* d_ws, size_t ws_size,
                              hipStream_t stream)
{
    const float* event_out = (const float*)d_in[0];
    const int*   et        = (const int*)d_in[1];
    const int*   labsp     = (const int*)d_in[2];
    const int S = in_sizes[1] / E_CONST;             // 8192

    const size_t colElems = (size_t)E_CONST * T_CONST * S;
    const size_t esElems  = (size_t)E_CONST * S;

    char* p = (char*)d_ws;
    float* cumT   = (float*)p; p += colElems * 4;
    float* expF   = (float*)p; p += colElems * 4;
    float* expB   = (float*)p; p += colElems * 4;
    int*   perm   = (int*)p;   p += esElems * 4;
    int*   permB  = (int*)p;   p += esElems * 4;
    int*   tlP    = (int*)p;   p += esElems * 4;
    int*   fstart = (int*)p;   p += E_CONST * T_CONST * 4;
    int*   b1end  = (int*)p;   p += E_CONST * T_CONST * 4;
    int*   histK  = (int*)p;   p += E_CONST * 2 * T_CONST * 4;  // histB follows
    int*   histB  = (int*)p;   p += E_CONST * T_CONST * 4;      // contiguous!
    int*   cursK  = (int*)p;   p += E_CONST * 2 * T_CONST * 4;
    int*   cursB  = (int*)p;   p += E_CONST * T_CONST * 4;
    float* acc    = (float*)p; p += 64;
    const size_t needed = (size_t)(p - (char*)d_ws);

    bool coop_ok = (ws_size >= needed);
    int grid = 0;
    if (coop_ok) {
        int maxPerCU = 0, numCU = 0;
        if (hipOccupancyMaxActiveBlocksPerMultiprocessor(
                &maxPerCU, (const void*)fused_kernel, 256, 0) != hipSuccess)
            maxPerCU = 0;
        if (hipDeviceGetAttribute(&numCU, hipDeviceAttributeMultiprocessorCount, 0)
                != hipSuccess)
            numCU = 0;
        grid = maxPerCU * numCU;
        if (grid > 512) grid = 512;
        if (grid < 96) coop_ok = false;   // need nThreads>=E*S/.. and sane residency
    }

    if (coop_ok) {
        Ptrs P;
        P.event_out = event_out; P.et = et; P.labs = labsp;
        P.cumT = cumT; P.expF = expF; P.expB = expB;
        P.perm = perm; P.permB = permB; P.tlP = tlP;
        P.fstart = fstart; P.b1end = b1end;
        P.histK = histK; P.histB = histB; P.cursK = cursK; P.cursB = cursB;
        P.acc = acc; P.out = (float*)d_out; P.S = S;
        void* kargs[] = { (void*)&P };
        hipError_t err = hipLaunchCooperativeKernel(
            (const void*)fused_kernel, dim3(grid), dim3(256), kargs, 0, stream);
        if (err == hipSuccess) return;
        // else fall through to the multi-kernel path
    }

    // ---------------- fallback: R1-style proven path ----------------
    {
        float* cumT2     = (float*)d_ws;
        int*   tlA2      = (int*)(cumT2 + colElems);
        float* partials2 = (float*)(tlA2 + esElems);
        const int nB = E_CONST * S;
        hipLaunchKernelGGL(prep_kernel, dim3(E_CONST * S / 64), dim3(64), 0, stream,
                           event_out, et, labsp, cumT2, tlA2, S);
        hipLaunchKernelGGL(pair_kernel, dim3(nB), dim3(256), 0, stream,
                           cumT2, tlA2, partials2, S);
        hipLaunchKernelGGL(reduce_kernel, dim3(1), dim3(1024), 0, stream,
                           partials2, nB, (float*)d_out);
    }
}